// Round 1
// baseline (3437.414 us; speedup 1.0000x reference)
//
#include <hip/hip_runtime.h>

// ---------------------------------------------------------------------------
// Sparse 3D U-Net backbone (MinkowskiEngine-style), fp32 reference-accurate.
// Round 1: correctness-first. Gather -> LDS -> register-tiled GEMM ->
// atomicAdd scatter, per 27-offset kernel map. BN two-pass. Worst-case grids
// with device-side n1/n2/n3 bounds (host never sees them).
// ---------------------------------------------------------------------------

__global__ void zero_rows_k(float* __restrict__ buf, int ld, int cols, int lc,
                            const int* __restrict__ ndev, int nhost) {
  const int n = (nhost >= 0) ? nhost : __ldg(ndev);
  const long total = (long)(n + 1) * cols;  // include pad/dump row
  const long stride = (long)gridDim.x * blockDim.x;
  for (long i = (long)blockIdx.x * blockDim.x + threadIdx.x; i < total; i += stride) {
    const long r = i >> lc;
    const int c = (int)(i & (cols - 1));
    buf[r * ld + c] = 0.0f;
  }
}

// Sparse conv over 27 offsets: out[om[k,p]] += fp[im[k,p]] @ W[k]
// fp: [n_in+1, CIN] with zeroed pad row (unless nin_bound>=0, then OOB reads
// are replaced by 0 in the gather). out: [n_out+1, ldo], pre-zeroed cols.
template <int CIN, int COUT, int TP, int RM, int RN>
__global__ __launch_bounds__(256) void sconv_k(
    const float* __restrict__ fp, const float* __restrict__ W,
    const int* __restrict__ imap, const int* __restrict__ omap, const int P,
    const int* __restrict__ ndev, const int nhost, const int nin_bound,
    float* __restrict__ out, const int ldo) {
  constexpr int NTX = COUT / RN;
  constexpr int NTY = 256 / NTX;
  static_assert(NTX * RN == COUT, "cols");
  static_assert(NTY * RM == TP, "rows");
  static_assert(CIN % 4 == 0, "cin vec");
  static_assert(RN % 4 == 0, "rn vec");
  constexpr int LPR = CIN / 4;  // float4 loads per gathered row

  const int k = blockIdx.y;
  const int t0 = blockIdx.x * TP;
  const int nout = (nhost >= 0) ? nhost : __ldg(ndev);
  const int* __restrict__ im = imap + (long)k * P;
  const int* __restrict__ om = omap + (long)k * P;
  // padding is trailing within each offset row; pad out-index == nout
  if (__ldg(om + t0) >= nout) return;

  __shared__ float a[TP][CIN + 4];
  __shared__ int oidx[TP];

  if (threadIdx.x < TP) {
    const int p = t0 + threadIdx.x;
    oidx[threadIdx.x] = (p < P) ? om[p] : nout;  // beyond-P -> dump row
  }
  for (int s = threadIdx.x; s < TP * LPR; s += 256) {
    const int r = s / LPR;
    const int q = s - r * LPR;
    const int p = t0 + r;
    float4 v = make_float4(0.f, 0.f, 0.f, 0.f);
    if (p < P) {
      const int i = im[p];
      if (nin_bound < 0 || i < nin_bound)
        v = *reinterpret_cast<const float4*>(fp + (long)i * CIN + (q << 2));
    }
    *reinterpret_cast<float4*>(&a[r][q << 2]) = v;
  }
  __syncthreads();

  const int tx = threadIdx.x % NTX;
  const int ty = threadIdx.x / NTX;
  float acc[RM][RN] = {};
  const float* __restrict__ Wk = W + (long)k * CIN * COUT + tx * RN;

  for (int ci = 0; ci < CIN; ++ci) {
    float wv[RN];
#pragma unroll
    for (int j = 0; j < RN; j += 4) {
      const float4 w4 = *reinterpret_cast<const float4*>(Wk + (long)ci * COUT + j);
      wv[j + 0] = w4.x; wv[j + 1] = w4.y; wv[j + 2] = w4.z; wv[j + 3] = w4.w;
    }
#pragma unroll
    for (int m = 0; m < RM; ++m) {
      const float av = a[ty * RM + m][ci];
#pragma unroll
      for (int j = 0; j < RN; ++j) acc[m][j] = fmaf(av, wv[j], acc[m][j]);
    }
  }

#pragma unroll
  for (int m = 0; m < RM; ++m) {
    const int o = oidx[ty * RM + m];
    float* __restrict__ orow = out + (long)o * ldo + tx * RN;
#pragma unroll
    for (int j = 0; j < RN; ++j) atomicAdd(orow + j, acc[m][j]);
  }
}

// per-channel sum / sumsq over rows [0, n)
template <int C>
__global__ __launch_bounds__(256) void bn_stats_k(
    const float* __restrict__ x, int ld, const int* __restrict__ ndev, int nhost,
    float* __restrict__ sums) {
  constexpr int RPB = 256 / C;
  const int n = (nhost >= 0) ? nhost : __ldg(ndev);
  const int c = threadIdx.x % C;
  const int rsub = threadIdx.x / C;
  float s = 0.f, ss = 0.f;
  const long step = (long)gridDim.x * RPB;
  for (long r = (long)blockIdx.x * RPB + rsub; r < n; r += step) {
    const float v = x[r * ld + c];
    s += v;
    ss = fmaf(v, v, ss);
  }
  __shared__ float sh[2][256];
  sh[0][threadIdx.x] = s;
  sh[1][threadIdx.x] = ss;
  __syncthreads();
  if (rsub == 0) {
#pragma unroll
    for (int j = 1; j < RPB; ++j) {
      s += sh[0][c + j * C];
      ss += sh[1][c + j * C];
    }
    atomicAdd(&sums[c], s);
    atomicAdd(&sums[C + c], ss);
  }
}

__global__ void bn_finalize_k(const float* __restrict__ sums,
                              const float* __restrict__ g, const float* __restrict__ b,
                              const int* __restrict__ ndev, int nhost, int C,
                              float* __restrict__ sb) {
  const int c = threadIdx.x;
  if (c >= C) return;
  const float n = (float)((nhost >= 0) ? nhost : __ldg(ndev));
  const float mean = sums[c] / n;
  const float var = sums[C + c] / n - mean * mean;
  const float sc = g[c] * rsqrtf(var + 1e-5f);
  sb[c] = sc;
  sb[C + c] = fmaf(-mean, sc, b[c]);
}

__global__ void bn_apply_k(float* __restrict__ x, int ld, int cols, int lc,
                           const float* __restrict__ sb,
                           const int* __restrict__ ndev, int nhost) {
  const int n = (nhost >= 0) ? nhost : __ldg(ndev);
  const long total = (long)n * cols;  // rows < n only (pad row stays 0)
  const long stride = (long)gridDim.x * blockDim.x;
  for (long i = (long)blockIdx.x * blockDim.x + threadIdx.x; i < total; i += stride) {
    const long r = i >> lc;
    const int c = (int)(i & (cols - 1));
    const float v = x[r * ld + c];
    x[r * ld + c] = fmaxf(fmaf(v, sb[c], sb[cols + c]), 0.f);
  }
}

__global__ void copy_cols_k(const float* __restrict__ src, int lsrc,
                            float* __restrict__ dst, int ldst, int cols, int lc,
                            const int* __restrict__ ndev, int nhost) {
  const int n = (nhost >= 0) ? nhost : __ldg(ndev);
  const long total = (long)(n + 1) * cols;  // include pad row (zeros)
  const long stride = (long)gridDim.x * blockDim.x;
  for (long i = (long)blockIdx.x * blockDim.x + threadIdx.x; i < total; i += stride) {
    const long r = i >> lc;
    const int c = (int)(i & (cols - 1));
    dst[r * ldst + c] = src[r * lsrc + c];
  }
}

// out[N0,20] = d2[N0,64] @ Wf[64,20]
__global__ __launch_bounds__(256) void final_gemm_k(
    const float* __restrict__ d2, const float* __restrict__ Wf,
    float* __restrict__ out, int n0) {
  __shared__ float w[64 * 20];
  for (int i = threadIdx.x; i < 64 * 20; i += 256) w[i] = Wf[i];
  __syncthreads();
  const int r = blockIdx.x * 256 + threadIdx.x;
  if (r >= n0) return;
  const float* __restrict__ row = d2 + (long)r * 64;
  float acc[20];
#pragma unroll
  for (int c = 0; c < 20; ++c) acc[c] = 0.f;
#pragma unroll
  for (int j = 0; j < 64; j += 4) {
    const float4 v = *reinterpret_cast<const float4*>(row + j);
    const float vv[4] = {v.x, v.y, v.z, v.w};
#pragma unroll
    for (int u = 0; u < 4; ++u) {
#pragma unroll
      for (int c = 0; c < 20; ++c) acc[c] = fmaf(vv[u], w[(j + u) * 20 + c], acc[c]);
    }
  }
  float* __restrict__ orow = out + (long)r * 20;
#pragma unroll
  for (int c = 0; c < 20; ++c) orow[c] = acc[c];
}

// ---------------------------------------------------------------------------

extern "C" void kernel_launch(void* const* d_in, const int* in_sizes, int n_in,
                              void* d_out, int out_size, void* d_ws, size_t ws_size,
                              hipStream_t stream) {
  const float* feats = (const float*)d_in[0];
  const float* W1 = (const float*)d_in[1];
  const float* W2 = (const float*)d_in[2];
  const float* W3 = (const float*)d_in[3];
  const float* W4 = (const float*)d_in[4];
  const float* D4w = (const float*)d_in[5];
  const float* D3w = (const float*)d_in[6];
  const float* D2w = (const float*)d_in[7];
  const float* Wf = (const float*)d_in[8];
  const float* g1 = (const float*)d_in[9];   const float* b1 = (const float*)d_in[10];
  const float* g2 = (const float*)d_in[11];  const float* b2 = (const float*)d_in[12];
  const float* g3 = (const float*)d_in[13];  const float* b3 = (const float*)d_in[14];
  const float* g4 = (const float*)d_in[15];  const float* b4 = (const float*)d_in[16];
  const float* gd4 = (const float*)d_in[17]; const float* bd4 = (const float*)d_in[18];
  const float* gd3 = (const float*)d_in[19]; const float* bd3 = (const float*)d_in[20];
  const float* gd2 = (const float*)d_in[21]; const float* bd2 = (const float*)d_in[22];
  const int* m1i = (const int*)d_in[23]; const int* m1o = (const int*)d_in[24];
  const int* m2i = (const int*)d_in[25]; const int* m2o = (const int*)d_in[26];
  const int* m3i = (const int*)d_in[27]; const int* m3o = (const int*)d_in[28];
  const int* m4i = (const int*)d_in[29]; const int* m4o = (const int*)d_in[30];
  const int* n1d = (const int*)d_in[31];
  const int* n2d = (const int*)d_in[32];
  const int* n3d = (const int*)d_in[33];

  const int N0 = in_sizes[0] / 4;
  const int P1 = in_sizes[23] / 27;
  const int P2 = in_sizes[25] / 27;
  const int P3 = in_sizes[27] / 27;
  const int P4 = in_sizes[29] / 27;

  const int MAXN1 = N0;
  const int MAXN2 = (N0 < 65536) ? N0 : 65536;  // 2 * 32^3
  const int MAXN3 = (N0 < 8192) ? N0 : 8192;    // 2 * 16^3

  float* ws = (float*)d_ws;
  size_t off = 0;
  auto alloc = [&](size_t nf) {
    float* p = ws + off;
    off += (nf + 63) & ~(size_t)63;
    return p;
  };
  float* e1 = alloc((size_t)(N0 + 1) * 32);
  float* e2 = alloc((size_t)(MAXN1 + 1) * 64);
  float* e3 = alloc((size_t)(MAXN2 + 1) * 128);
  float* e4 = alloc((size_t)(MAXN3 + 1) * 256);
  float* d4 = alloc((size_t)(MAXN2 + 1) * 256);
  float* d3 = alloc((size_t)(MAXN1 + 1) * 128);
  float* stats = alloc(7 * 1024);
  float* dd2 = d4;  // alias: d4 is dead before dd2 is first written
  if (off * sizeof(float) > ws_size) return;  // insufficient workspace -> loud fail

  hipMemsetAsync(stats, 0, 7 * 1024 * sizeof(float), stream);
  const dim3 blk(256);
#define ST(i) (stats + (i)*1024)
#define SB(i) (stats + (i)*1024 + 512)

  // ---- encoder layer 1: conv(4->32), stride 1, out rows N0 ----
  zero_rows_k<<<1024, blk, 0, stream>>>(e1, 32, 32, 5, nullptr, N0);
  sconv_k<4, 32, 64, 2, 4><<<dim3((P1 + 63) / 64, 27), blk, 0, stream>>>(
      feats, W1, m1i, m1o, P1, nullptr, N0, N0, e1, 32);
  bn_stats_k<32><<<512, blk, 0, stream>>>(e1, 32, nullptr, N0, ST(0));
  bn_finalize_k<<<1, blk, 0, stream>>>(ST(0), g1, b1, nullptr, N0, 32, SB(0));
  bn_apply_k<<<1024, blk, 0, stream>>>(e1, 32, 32, 5, SB(0), nullptr, N0);

  // ---- encoder layer 2: conv(32->64), stride 2, out rows n1 ----
  zero_rows_k<<<1024, blk, 0, stream>>>(e2, 64, 64, 6, n1d, -1);
  sconv_k<32, 64, 64, 4, 4><<<dim3((P2 + 63) / 64, 27), blk, 0, stream>>>(
      e1, W2, m2i, m2o, P2, n1d, -1, -1, e2, 64);
  bn_stats_k<64><<<512, blk, 0, stream>>>(e2, 64, n1d, -1, ST(1));
  bn_finalize_k<<<1, blk, 0, stream>>>(ST(1), g2, b2, n1d, -1, 64, SB(1));
  bn_apply_k<<<1024, blk, 0, stream>>>(e2, 64, 64, 6, SB(1), n1d, -1);

  // ---- encoder layer 3: conv(64->128), stride 2, out rows n2 ----
  zero_rows_k<<<1024, blk, 0, stream>>>(e3, 128, 128, 7, n2d, -1);
  sconv_k<64, 128, 64, 8, 4><<<dim3((P3 + 63) / 64, 27), blk, 0, stream>>>(
      e2, W3, m3i, m3o, P3, n2d, -1, -1, e3, 128);
  bn_stats_k<128><<<512, blk, 0, stream>>>(e3, 128, n2d, -1, ST(2));
  bn_finalize_k<<<1, blk, 0, stream>>>(ST(2), g3, b3, n2d, -1, 128, SB(2));
  bn_apply_k<<<1024, blk, 0, stream>>>(e3, 128, 128, 7, SB(2), n2d, -1);

  // ---- encoder layer 4: conv(128->256), stride 2, out rows n3 ----
  zero_rows_k<<<256, blk, 0, stream>>>(e4, 256, 256, 8, n3d, -1);
  sconv_k<128, 256, 32, 4, 8><<<dim3((P4 + 31) / 32, 27), blk, 0, stream>>>(
      e3, W4, m4i, m4o, P4, n3d, -1, -1, e4, 256);
  bn_stats_k<256><<<512, blk, 0, stream>>>(e4, 256, n3d, -1, ST(3));
  bn_finalize_k<<<1, blk, 0, stream>>>(ST(3), g4, b4, n3d, -1, 256, SB(3));
  bn_apply_k<<<512, blk, 0, stream>>>(e4, 256, 256, 8, SB(3), n3d, -1);

  // ---- decoder D4: tconv(256->128) into d4[:, :128], concat e3 -> cols 128: ----
  zero_rows_k<<<1024, blk, 0, stream>>>(d4, 256, 128, 7, n2d, -1);
  sconv_k<256, 128, 32, 4, 4><<<dim3((P4 + 31) / 32, 27), blk, 0, stream>>>(
      e4, D4w, m4o, m4i, P4, n2d, -1, -1, d4, 256);
  bn_stats_k<128><<<512, blk, 0, stream>>>(d4, 256, n2d, -1, ST(4));
  bn_finalize_k<<<1, blk, 0, stream>>>(ST(4), gd4, bd4, n2d, -1, 128, SB(4));
  bn_apply_k<<<1024, blk, 0, stream>>>(d4, 256, 128, 7, SB(4), n2d, -1);
  copy_cols_k<<<1024, blk, 0, stream>>>(e3, 128, d4 + 128, 256, 128, 7, n2d, -1);

  // ---- decoder D3: tconv(256->64) into d3[:, :64], concat e2 ----
  zero_rows_k<<<1024, blk, 0, stream>>>(d3, 128, 64, 6, n1d, -1);
  sconv_k<256, 64, 32, 2, 4><<<dim3((P3 + 31) / 32, 27), blk, 0, stream>>>(
      d4, D3w, m3o, m3i, P3, n1d, -1, -1, d3, 128);
  bn_stats_k<64><<<512, blk, 0, stream>>>(d3, 128, n1d, -1, ST(5));
  bn_finalize_k<<<1, blk, 0, stream>>>(ST(5), gd3, bd3, n1d, -1, 64, SB(5));
  bn_apply_k<<<1024, blk, 0, stream>>>(d3, 128, 64, 6, SB(5), n1d, -1);
  copy_cols_k<<<1024, blk, 0, stream>>>(e2, 64, d3 + 64, 128, 64, 6, n1d, -1);

  // ---- decoder D2: tconv(128->32) into dd2[:, :32], concat e1 ----
  zero_rows_k<<<1024, blk, 0, stream>>>(dd2, 64, 32, 5, nullptr, N0);
  sconv_k<128, 32, 64, 2, 4><<<dim3((P2 + 63) / 64, 27), blk, 0, stream>>>(
      d3, D2w, m2o, m2i, P2, nullptr, N0, -1, dd2, 64);
  bn_stats_k<32><<<512, blk, 0, stream>>>(dd2, 64, nullptr, N0, ST(6));
  bn_finalize_k<<<1, blk, 0, stream>>>(ST(6), gd2, bd2, nullptr, N0, 32, SB(6));
  bn_apply_k<<<1024, blk, 0, stream>>>(dd2, 64, 32, 5, SB(6), nullptr, N0);
  copy_cols_k<<<1024, blk, 0, stream>>>(e1, 32, dd2 + 32, 64, 32, 5, nullptr, N0);

  // ---- final 1x1: out = dd2 @ Wf ----
  final_gemm_k<<<(N0 + 255) / 256, blk, 0, stream>>>(dd2, Wf, (float*)d_out, N0);

#undef ST
#undef SB
}